// Round 4
// baseline (1332.180 us; speedup 1.0000x reference)
//
#include <hip/hip_runtime.h>
#include <cstdint>
#include <math.h>

typedef _Float16 f16;
typedef f16 f16x8 __attribute__((ext_vector_type(8)));
typedef f16 f16x4 __attribute__((ext_vector_type(4)));
typedef float f32x4 __attribute__((ext_vector_type(4)));

#define BATCH 2
#define TSEQ 4096
#define WID 2048
#define LRU 2048
#define NHEAD 8
#define HDIM 256
#define MTOT (BATCH * TSEQ)   // 8192
#define NCHUNK 32             // chunks per batch (CT = 128 rows)
#define NMT 64                // total m-tiles (= chunks over both batches)

// ---------- async global -> LDS, 16B per lane ----------
__device__ __forceinline__ void gl2lds16(const f16* g, f16* l) {
  __builtin_amdgcn_global_load_lds(
      (__attribute__((address_space(1))) uint32_t*)(uintptr_t)g,
      (__attribute__((address_space(3))) uint32_t*)(uint32_t)(uintptr_t)l,
      16, 0, 0);
}

__device__ __forceinline__ float sigmoidf_(float x) { return 1.f / (1.f + expf(-x)); }

// ---------- prep megakernel: cast x -> f16, transpose+cast all weights ----------
// blocks [0,16384): cast; [16384, 28672): 3x 2048^2 transpose; [28672, 29696): 16x 256^2
__global__ void prep_kernel(const float* __restrict__ x, f16* __restrict__ Xh,
                            const float* __restrict__ w_y, const float* __restrict__ w_x,
                            const float* __restrict__ w_out,
                            f16* __restrict__ wyT, f16* __restrict__ wxT, f16* __restrict__ woutT,
                            const float* __restrict__ ig, const float* __restrict__ ag,
                            f16* __restrict__ igT, f16* __restrict__ agT) {
  __shared__ float tile[32][33];
  const int bid = blockIdx.x, t = threadIdx.x;
  if (bid < 16384) {
    int i = bid * 256 + t;
    float4 v = ((const float4*)x)[i];
    f16x4 o = { (f16)v.x, (f16)v.y, (f16)v.z, (f16)v.w };
    ((f16x4*)Xh)[i] = o;
    return;
  }
  const int tx = t & 31, ty = t >> 5;
  const float* ib; f16* ob; int R, C, c0, r0;
  if (bid < 28672) {
    int idx = bid - 16384;
    int z = idx >> 12, tl = idx & 4095;
    ib = z == 0 ? w_y : (z == 1 ? w_x : w_out);
    ob = z == 0 ? wyT : (z == 1 ? wxT : woutT);
    R = 2048; C = 2048;
    c0 = (tl & 63) * 32; r0 = (tl >> 6) * 32;
  } else {
    int idx = bid - 28672;
    int z = idx >> 6, tl = idx & 63;
    ib = (z < 8 ? ig : ag) + (long long)(z & 7) * HDIM * HDIM;
    ob = (z < 8 ? igT : agT) + (long long)(z & 7) * HDIM * HDIM;
    R = HDIM; C = HDIM;
    c0 = (tl & 7) * 32; r0 = (tl >> 3) * 32;
  }
#pragma unroll
  for (int i = 0; i < 32; i += 8)
    tile[ty + i][tx] = ib[(long long)(r0 + ty + i) * C + c0 + tx];
  __syncthreads();
#pragma unroll
  for (int i = 0; i < 32; i += 8)
    ob[(long long)(c0 + ty + i) * R + r0 + tx] = (f16)tile[tx][ty + i];
}

// ---------- fused dual-B input GEMM ----------
// A [M,K], B1T/B2T [N,K] f16. Y = gelu_tanh(A@B1 + b1) f16; X2 = (A@B2 + b2) f16.
__global__ __launch_bounds__(256, 2) void gemm_dual(
    const f16* __restrict__ A, const f16* __restrict__ B1T, const f16* __restrict__ B2T,
    const float* __restrict__ b1, const float* __restrict__ b2,
    f16* __restrict__ Y, f16* __restrict__ X2, int M, int N, int K) {
  __shared__ __align__(16) f16 As[128 * 32];
  __shared__ __align__(16) f16 B1s[128 * 32];
  __shared__ __align__(16) f16 B2s[128 * 32];
  const int m0 = blockIdx.x * 128, n0 = blockIdx.y * 128;
  const int t = threadIdx.x;
  const int lane = t & 63, wave = t >> 6;
  const int wr = (wave >> 1) * 64, wc = (wave & 1) * 64;
  const int l15 = lane & 15, quad = lane >> 4;
  const int srow = t >> 2, scol = (t & 3) * 8;

  const f16* Ag = A + (long long)(m0 + srow) * K + scol;
  const f16* B1g = B1T + (long long)(n0 + srow) * K + scol;
  const f16* B2g = B2T + (long long)(n0 + srow) * K + scol;

  f32x4 c1[4][4] = {};
  f32x4 c2[4][4] = {};
  for (int k0 = 0; k0 < K; k0 += 32) {
    gl2lds16(Ag, &As[t * 8]);   gl2lds16(Ag + (long long)64 * K, &As[64 * 32 + t * 8]);
    gl2lds16(B1g, &B1s[t * 8]); gl2lds16(B1g + (long long)64 * K, &B1s[64 * 32 + t * 8]);
    gl2lds16(B2g, &B2s[t * 8]); gl2lds16(B2g + (long long)64 * K, &B2s[64 * 32 + t * 8]);
    Ag += 32; B1g += 32; B2g += 32;
    __syncthreads();
    f16x8 af[4], b1f[4], b2f[4];
#pragma unroll
    for (int i = 0; i < 4; ++i)
      af[i] = *(const f16x8*)&As[(wr + i * 16 + l15) * 32 + quad * 8];
#pragma unroll
    for (int j = 0; j < 4; ++j) {
      b1f[j] = *(const f16x8*)&B1s[(wc + j * 16 + l15) * 32 + quad * 8];
      b2f[j] = *(const f16x8*)&B2s[(wc + j * 16 + l15) * 32 + quad * 8];
    }
#pragma unroll
    for (int i = 0; i < 4; ++i)
#pragma unroll
      for (int j = 0; j < 4; ++j) {
        c1[i][j] = __builtin_amdgcn_mfma_f32_16x16x32_f16(af[i], b1f[j], c1[i][j], 0, 0, 0);
        c2[i][j] = __builtin_amdgcn_mfma_f32_16x16x32_f16(af[i], b2f[j], c2[i][j], 0, 0, 0);
      }
    __syncthreads();
  }
#pragma unroll
  for (int i = 0; i < 4; ++i) {
#pragma unroll
    for (int j = 0; j < 4; ++j) {
      const int col = n0 + wc + j * 16 + l15;
      const float b1v = b1[col], b2v = b2[col];
      const int row0 = m0 + wr + i * 16 + quad * 4;
#pragma unroll
      for (int r = 0; r < 4; ++r) {
        long long off = (long long)(row0 + r) * N + col;
        float v = c1[i][j][r] + b1v;
        float u = v + 0.044715f * v * v * v;
        float g = 0.5f * v * (1.f + tanhf(0.7978845608028654f * u));
        Y[off] = (f16)g;
        X2[off] = (f16)(c2[i][j][r] + b2v);
      }
    }
  }
}

// ---------- GEMM: C[M,N] = A[M,K] @ BT[N,K]^T + bias (fp32 out) ----------
__global__ __launch_bounds__(256, 2) void gemm_bt(
    const f16* __restrict__ A, const f16* __restrict__ BT, const float* __restrict__ bias,
    float* __restrict__ Cf, int M, int N, int K) {
  __shared__ __align__(16) f16 As[128 * 32];
  __shared__ __align__(16) f16 Bs[128 * 32];
  const int m0 = blockIdx.x * 128, n0 = blockIdx.y * 128;
  const int t = threadIdx.x;
  const int lane = t & 63, wave = t >> 6;
  const int wr = (wave >> 1) * 64, wc = (wave & 1) * 64;
  const int l15 = lane & 15, quad = lane >> 4;
  const int srow = t >> 2, scol = (t & 3) * 8;

  const f16* Ag = A + (long long)(m0 + srow) * K + scol;
  const f16* Bg = BT + (long long)(n0 + srow) * K + scol;

  f32x4 acc[4][4] = {};
  for (int k0 = 0; k0 < K; k0 += 32) {
    gl2lds16(Ag, &As[t * 8]); gl2lds16(Ag + (long long)64 * K, &As[64 * 32 + t * 8]);
    gl2lds16(Bg, &Bs[t * 8]); gl2lds16(Bg + (long long)64 * K, &Bs[64 * 32 + t * 8]);
    Ag += 32; Bg += 32;
    __syncthreads();
    f16x8 af[4], bf[4];
#pragma unroll
    for (int i = 0; i < 4; ++i)
      af[i] = *(const f16x8*)&As[(wr + i * 16 + l15) * 32 + quad * 8];
#pragma unroll
    for (int j = 0; j < 4; ++j)
      bf[j] = *(const f16x8*)&Bs[(wc + j * 16 + l15) * 32 + quad * 8];
#pragma unroll
    for (int i = 0; i < 4; ++i)
#pragma unroll
      for (int j = 0; j < 4; ++j)
        acc[i][j] = __builtin_amdgcn_mfma_f32_16x16x32_f16(af[i], bf[j], acc[i][j], 0, 0, 0);
    __syncthreads();
  }
#pragma unroll
  for (int i = 0; i < 4; ++i) {
#pragma unroll
    for (int j = 0; j < 4; ++j) {
      const int col = n0 + wc + j * 16 + l15;
      const float bv = bias[col];
      const int row0 = m0 + wr + i * 16 + quad * 4;
#pragma unroll
      for (int r = 0; r < 4; ++r)
        Cf[(long long)(row0 + r) * N + col] = acc[i][j][r] + bv;
    }
  }
}

// ---------- fused conv + gates GEMM + RG-LRU + FULL scan (decoupled look-back) ----------
// Grid: 1024 blocks, ticket-ordered. Virtual id v: b=v&1, cg=(v>>1)&15, chunk=v>>5.
// Emits G = h * gelu_y directly. Chain carries h_end per (mt, colgroup) through global mem.
__global__ __launch_bounds__(256, 2) void gates_scan(
    const f16* __restrict__ XBh, const float* __restrict__ cw, const float* __restrict__ cb,
    const f16* __restrict__ BiT, const f16* __restrict__ BaT,
    const float* __restrict__ ib, const float* __restrict__ ab,
    const float* __restrict__ a_param, const int* __restrict__ segpos,
    const f16* __restrict__ Yh, f16* __restrict__ G,
    int* __restrict__ ticket, int* __restrict__ Flags, float* __restrict__ Carry) {
  __shared__ __align__(16) f16 As[128 * 256];   // 64 KB conv'd A tile, swizzled granules
  __shared__ __align__(16) f16 Bi[128 * 32];    // 8 KB
  __shared__ __align__(16) f16 Ba[128 * 32];    // 8 KB -> 80 KB total, 2 blocks/CU
  const int t = threadIdx.x;
  const int lane = t & 63, wave = t >> 6;
  const int wr = (wave >> 1) * 64, wc = (wave & 1) * 64;
  const int l15 = lane & 15, quad = lane >> 4;

  // ---- ticket: virtual block id (start-order monotone => deadlock-free chain) ----
  if (t == 0) ((int*)Bi)[0] = atomicAdd(ticket, 1);
  __syncthreads();
  const int v = ((int*)Bi)[0];
  const int bz = v & 1, cg = (v >> 1) & 15, chunk = v >> 5;
  const int mt = bz * NCHUNK + chunk;
  const int m0 = mt * 128;
  const int h = cg >> 1, half = cg & 1;
  const int ncol0 = h * HDIM + half * 128;
  const int mtcg = mt * 16 + cg;

  // ---- strip-mined conv prologue: As[r][k] = conv(m0+r, h*256+k) ----
#pragma unroll
  for (int it = 0; it < 2; ++it) {
    int idx = it * 256 + t;
    int kc = idx & 31;                     // granule col (8 f16)
    int r0 = (idx >> 5) * 8;               // strip start row
    int colbase = h * HDIM + kc * 8;
    f16x8 gr[11];
#pragma unroll
    for (int gi = 0; gi < 11; ++gi) {
      f16x8 g = {};
      int m = m0 + r0 - 3 + gi;
      if (m >= 0) g = *(const f16x8*)&XBh[(long long)m * LRU + colbase];
      gr[gi] = g;
    }
    float4 cb0 = *(const float4*)&cb[colbase];
    float4 cb1 = *(const float4*)&cb[colbase + 4];
    float4 w0[4], w1[4];
#pragma unroll
    for (int dd = 0; dd < 4; ++dd) {
      w0[dd] = *(const float4*)&cw[dd * LRU + colbase];
      w1[dd] = *(const float4*)&cw[dd * LRU + colbase + 4];
    }
#pragma unroll
    for (int r = 0; r < 8; ++r) {
      int rr = r0 + r;
      int m = m0 + rr, tpos = m & (TSEQ - 1);
      float acc[8] = {cb0.x, cb0.y, cb0.z, cb0.w, cb1.x, cb1.y, cb1.z, cb1.w};
#pragma unroll
      for (int d = 0; d < 4; ++d) {
        if (tpos >= d) {
          f16x8 xv = gr[3 + r - d];
          float4 a0 = w0[3 - d], a1 = w1[3 - d];
          acc[0] += a0.x * (float)xv[0]; acc[1] += a0.y * (float)xv[1];
          acc[2] += a0.z * (float)xv[2]; acc[3] += a0.w * (float)xv[3];
          acc[4] += a1.x * (float)xv[4]; acc[5] += a1.y * (float)xv[5];
          acc[6] += a1.z * (float)xv[6]; acc[7] += a1.w * (float)xv[7];
        }
      }
      f16x8 o;
#pragma unroll
      for (int k = 0; k < 8; ++k) o[k] = (f16)acc[k];
      int gs = (kc & ~7) | ((kc ^ rr) & 7);
      *(f16x8*)&As[rr * 256 + gs * 8] = o;
    }
  }
  __syncthreads();

  // ---- dual gate GEMM over the head's 256 k-cols ----
  const int srow = t >> 2, scol = (t & 3) * 8;
  const f16* Big = BiT + (long long)(ncol0 + srow) * HDIM + scol;
  const f16* Bag = BaT + (long long)(ncol0 + srow) * HDIM + scol;
  f32x4 ci[4][4] = {};
  f32x4 ca[4][4] = {};
  for (int k0 = 0; k0 < HDIM; k0 += 32) {
    gl2lds16(Big, &Bi[t * 8]); gl2lds16(Big + 64 * HDIM, &Bi[64 * 32 + t * 8]);
    gl2lds16(Bag, &Ba[t * 8]); gl2lds16(Bag + 64 * HDIM, &Ba[64 * 32 + t * 8]);
    Big += 32; Bag += 32;
    __syncthreads();
    f16x8 af[4], bif[4], baf[4];
#pragma unroll
    for (int i = 0; i < 4; ++i) {
      int row = wr + i * 16 + l15;
      int g = (k0 >> 3) + quad;
      int gsw = (g & ~7) | ((g ^ row) & 7);
      af[i] = *(const f16x8*)&As[row * 256 + gsw * 8];
    }
#pragma unroll
    for (int j = 0; j < 4; ++j) {
      bif[j] = *(const f16x8*)&Bi[(wc + j * 16 + l15) * 32 + quad * 8];
      baf[j] = *(const f16x8*)&Ba[(wc + j * 16 + l15) * 32 + quad * 8];
    }
#pragma unroll
    for (int i = 0; i < 4; ++i)
#pragma unroll
      for (int j = 0; j < 4; ++j) {
        ci[i][j] = __builtin_amdgcn_mfma_f32_16x16x32_f16(af[i], bif[j], ci[i][j], 0, 0, 0);
        ca[i][j] = __builtin_amdgcn_mfma_f32_16x16x32_f16(af[i], baf[j], ca[i][j], 0, 0, 0);
      }
    __syncthreads();
  }

  // ---- per-element RG-LRU + hierarchical inclusive scan (rows = time) ----
  // After this phase: ci = h_incl (within this wave's 64 rows), ca = A_incl.
  float Aw[4], hw[4];
#pragma unroll
  for (int j = 0; j < 4; ++j) {
    const int cl = wc + j * 16 + l15;
    const int col = ncol0 + cl;
    const float ibv = ib[col], abv = ab[col];
    const float sp = log1pf(expf(a_param[col]));
    float A_E = 1.f, h_E = 0.f;
#pragma unroll
    for (int i = 0; i < 4; ++i) {
      float Aacc = 1.f, hacc = 0.f;
#pragma unroll
      for (int r = 0; r < 4; ++r) {
        const int rowL = wr + i * 16 + quad * 4 + r;
        const int row = m0 + rowL;
        float gx = sigmoidf_(ci[i][j][r] + ibv);
        float ga = sigmoidf_(ca[i][j][r] + abv);
        float la = -8.f * ga * sp;
        bool rs = (segpos[row] == 0);
        float a = rs ? 0.f : expf(la);
        float mult = rs ? 1.f : sqrtf(fmaxf(1.f - a * a, 0.f));
        int cfull = half * 128 + cl;
        int g = cfull >> 3, e = cfull & 7;
        int gsw = (g & ~7) | ((g ^ rowL) & 7);
        float cv = (float)As[rowL * 256 + gsw * 8 + e];
        float xv = cv * gx * mult;
        hacc = a * hacc + xv;
        Aacc = a * Aacc;
        ci[i][j][r] = hacc;          // 4-row inclusive h
        ca[i][j][r] = Aacc;          // 4-row inclusive A
      }
      // Kogge-Stone inclusive over quads (16-row tile)
      float A1 = Aacc, h1 = hacc;
      {
        int src = lane >= 16 ? lane - 16 : lane;
        float Ap = __shfl(A1, src), hp = __shfl(h1, src);
        if (quad >= 1) { h1 = A1 * hp + h1; A1 = A1 * Ap; }
        src = lane >= 32 ? lane - 32 : lane;
        Ap = __shfl(A1, src); hp = __shfl(h1, src);
        if (quad >= 2) { h1 = A1 * hp + h1; A1 = A1 * Ap; }
      }
      int srcx = lane >= 16 ? lane - 16 : lane;
      float Ae = __shfl(A1, srcx), he = __shfl(h1, srcx);
      if (quad == 0) { Ae = 1.f; he = 0.f; }
      float A_p = Ae * A_E;            // prefix before my 4-row block
      float h_p = Ae * h_E + he;
#pragma unroll
      for (int r = 0; r < 4; ++r) {
        float Ael = ca[i][j][r], hel = ci[i][j][r];
        ci[i][j][r] = Ael * h_p + hel;
        ca[i][j][r] = A_p * Ael;
      }
      float At3 = __shfl(A1, 48 + l15), ht3 = __shfl(h1, 48 + l15);  // 16-row total
      h_E = At3 * h_E + ht3;
      A_E = At3 * A_E;
    }
    Aw[j] = A_E; hw[j] = h_E;          // this wave's 64-row totals
  }

  // ---- cross-wave fold (rows 0-63 -> 64-127) via LDS (Ba reused) ----
  float2* carryW = (float2*)Ba;                 // 1 KB
  float* Pl = (float*)((char*)Ba + 4096);       // 512 B
  if (wr == 0 && quad == 0) {
#pragma unroll
    for (int j = 0; j < 4; ++j) {
      float2 cwv; cwv.x = Aw[j]; cwv.y = hw[j];
      carryW[wc + j * 16 + l15] = cwv;
    }
  }
  __syncthreads();
  float A_tot[4], h_tot[4];
  if (wr == 64) {
#pragma unroll
    for (int j = 0; j < 4; ++j) {
      float2 bb = carryW[wc + j * 16 + l15];
#pragma unroll
      for (int i = 0; i < 4; ++i)
#pragma unroll
        for (int r = 0; r < 4; ++r) {
          float Ael = ca[i][j][r];
          ci[i][j][r] = Ael * bb.y + ci[i][j][r];
          ca[i][j][r] = bb.x * Ael;
        }
      A_tot[j] = Aw[j] * bb.x;
      h_tot[j] = Aw[j] * bb.y + hw[j];
    }
  }

  // ---- look-back: wait for predecessor chunk's h_end ----
  if (chunk > 0) {
    if (t < 128) {
      const int* fl = &Flags[mtcg - 16];
      while (__hip_atomic_load(fl, __ATOMIC_ACQUIRE, __HIP_MEMORY_SCOPE_AGENT) == 0)
        __builtin_amdgcn_s_sleep(8);
      Pl[t] = __hip_atomic_load(&Carry[(long long)(mtcg - 16) * 128 + t],
                                __ATOMIC_RELAXED, __HIP_MEMORY_SCOPE_AGENT);
    }
  } else if (t < 128) {
    Pl[t] = 0.f;
  }
  __syncthreads();

  // ---- publish our h_end ASAP ----
  if (wr == 64 && quad == 0) {
#pragma unroll
    for (int j = 0; j < 4; ++j) {
      int cl = wc + j * 16 + l15;
      float hend = A_tot[j] * Pl[cl] + h_tot[j];
      __hip_atomic_store(&Carry[(long long)mtcg * 128 + cl], hend,
                         __ATOMIC_RELAXED, __HIP_MEMORY_SCOPE_AGENT);
    }
  }
  __threadfence();
  __syncthreads();
  if (t == 0)
    __hip_atomic_store(&Flags[mtcg], 1, __ATOMIC_RELEASE, __HIP_MEMORY_SCOPE_AGENT);

  // ---- apply carry, emit G = h * gelu_y ----
#pragma unroll
  for (int j = 0; j < 4; ++j) {
    const int cl = wc + j * 16 + l15;
    const int col = ncol0 + cl;
    const float P = Pl[cl];
#pragma unroll
    for (int i = 0; i < 4; ++i) {
#pragma unroll
      for (int r = 0; r < 4; ++r) {
        const int row = m0 + wr + i * 16 + quad * 4 + r;
        float hg = ca[i][j][r] * P + ci[i][j][r];
        long long off = (long long)row * LRU + col;
        G[off] = (f16)(hg * (float)Yh[off]);
      }
    }
  }
}

extern "C" void kernel_launch(void* const* d_in, const int* in_sizes, int n_in,
                              void* d_out, int out_size, void* d_ws, size_t ws_size,
                              hipStream_t stream) {
  (void)in_sizes; (void)n_in; (void)out_size; (void)ws_size;
  const float* x          = (const float*)d_in[0];
  const int*   segment_pos= (const int*)d_in[1];
  const float* w_y        = (const float*)d_in[2];
  const float* b_y        = (const float*)d_in[3];
  const float* w_x        = (const float*)d_in[4];
  const float* b_x        = (const float*)d_in[5];
  const float* w_out      = (const float*)d_in[6];
  const float* b_out      = (const float*)d_in[7];
  const float* conv_w     = (const float*)d_in[8];
  const float* conv_b     = (const float*)d_in[9];
  const float* a_param    = (const float*)d_in[10];
  const float* igate_w    = (const float*)d_in[11];
  const float* igate_b    = (const float*)d_in[12];
  const float* agate_w    = (const float*)d_in[13];
  const float* agate_b    = (const float*)d_in[14];
  float* out = (float*)d_out;

  char* base = (char*)d_ws;
  size_t off = 0;
  auto alloc = [&](size_t nbytes) -> void* {
    void* p = base + off;
    off = (off + nbytes + 255) & ~(size_t)255;
    return p;
  };
  f16*   Xh    = (f16*)alloc((size_t)MTOT * LRU * 2);
  f16*   Yh    = (f16*)alloc((size_t)MTOT * LRU * 2);
  f16*   XBh   = (f16*)alloc((size_t)MTOT * LRU * 2);
  f16*   wyT   = (f16*)alloc((size_t)WID * LRU * 2);
  f16*   wxT   = (f16*)alloc((size_t)WID * LRU * 2);
  f16*   woutT = (f16*)alloc((size_t)LRU * WID * 2);
  f16*   igwT  = (f16*)alloc((size_t)NHEAD * HDIM * HDIM * 2);
  f16*   agwT  = (f16*)alloc((size_t)NHEAD * HDIM * HDIM * 2);
  float* Carry = (float*)alloc((size_t)NMT * 16 * 128 * 4);   // 512 KB
  int*   Flags = (int*)alloc((size_t)NMT * 16 * 4 + 256);     // flags + ticket
  int*   ticket= Flags + NMT * 16;
  f16*   G     = Xh;   // Xh dead after gemm_dual

  // zero flags + ticket (re-poisoned to 0xAA before every timed launch)
  hipMemsetAsync(Flags, 0, (size_t)NMT * 16 * 4 + 4, stream);
  // prep: cast + all weight transposes in one launch
  prep_kernel<<<29696, 256, 0, stream>>>(x, Xh, w_y, w_x, w_out, wyT, wxT, woutT,
                                         igate_w, agate_w, igwT, agwT);
  // fused dual input GEMM (linear_y + gelu, linear_x)
  gemm_dual<<<dim3(MTOT / 128, LRU / 128), 256, 0, stream>>>(
      Xh, wyT, wxT, b_y, b_x, Yh, XBh, MTOT, LRU, WID);
  // fused conv + gates + RG-LRU + full scan + G emission (look-back chain)
  gates_scan<<<BATCH * 16 * NCHUNK, 256, 0, stream>>>(
      XBh, conv_w, conv_b, igwT, agwT, igate_b, agate_b, a_param, segment_pos,
      Yh, G, ticket, Flags, Carry);
  // output projection
  gemm_bt<<<dim3(MTOT / 128, WID / 128), 256, 0, stream>>>(G, woutT, b_out, out, MTOT, WID, LRU);
}

// Round 5
// 566.000 us; speedup vs baseline: 2.3537x; 2.3537x over previous
//
#include <hip/hip_runtime.h>
#include <cstdint>
#include <math.h>

typedef _Float16 f16;
typedef f16 f16x8 __attribute__((ext_vector_type(8)));
typedef f16 f16x4 __attribute__((ext_vector_type(4)));
typedef float f32x4 __attribute__((ext_vector_type(4)));

#define BATCH 2
#define TSEQ 4096
#define WID 2048
#define LRU 2048
#define NHEAD 8
#define HDIM 256
#define MTOT (BATCH * TSEQ)   // 8192
#define CT 128                // scan chunk length == gates m-tile
#define NC (TSEQ / CT)        // 32 chunks

// ---------- async global -> LDS, 16B per lane ----------
__device__ __forceinline__ void gl2lds16(const f16* g, f16* l) {
  __builtin_amdgcn_global_load_lds(
      (__attribute__((address_space(1))) uint32_t*)(uintptr_t)g,
      (__attribute__((address_space(3))) uint32_t*)(uint32_t)(uintptr_t)l,
      16, 0, 0);
}

__device__ __forceinline__ float sigmoidf_(float x) { return 1.f / (1.f + expf(-x)); }
__device__ __forceinline__ float f16bits_to_f(uint32_t b) {
  return (float)__builtin_bit_cast(f16, (uint16_t)b);
}

// ---------- prep megakernel: cast x -> f16, transpose+cast all weights ----------
// blocks [0,16384): cast; [16384, 28672): 3x 2048^2 transpose; [28672, 29696): 16x 256^2
__global__ void prep_kernel(const float* __restrict__ x, f16* __restrict__ Xh,
                            const float* __restrict__ w_y, const float* __restrict__ w_x,
                            const float* __restrict__ w_out,
                            f16* __restrict__ wyT, f16* __restrict__ wxT, f16* __restrict__ woutT,
                            const float* __restrict__ ig, const float* __restrict__ ag,
                            f16* __restrict__ igT, f16* __restrict__ agT) {
  __shared__ float tile[32][33];
  const int bid = blockIdx.x, t = threadIdx.x;
  if (bid < 16384) {
    int i = bid * 256 + t;
    float4 v = ((const float4*)x)[i];
    f16x4 o = { (f16)v.x, (f16)v.y, (f16)v.z, (f16)v.w };
    ((f16x4*)Xh)[i] = o;
    return;
  }
  const int tx = t & 31, ty = t >> 5;
  const float* ib; f16* ob; int R, C, c0, r0;
  if (bid < 28672) {
    int idx = bid - 16384;
    int z = idx >> 12, tl = idx & 4095;
    ib = z == 0 ? w_y : (z == 1 ? w_x : w_out);
    ob = z == 0 ? wyT : (z == 1 ? wxT : woutT);
    R = 2048; C = 2048;
    c0 = (tl & 63) * 32; r0 = (tl >> 6) * 32;
  } else {
    int idx = bid - 28672;
    int z = idx >> 6, tl = idx & 63;
    ib = (z < 8 ? ig : ag) + (long long)(z & 7) * HDIM * HDIM;
    ob = (z < 8 ? igT : agT) + (long long)(z & 7) * HDIM * HDIM;
    R = HDIM; C = HDIM;
    c0 = (tl & 7) * 32; r0 = (tl >> 3) * 32;
  }
#pragma unroll
  for (int i = 0; i < 32; i += 8)
    tile[ty + i][tx] = ib[(long long)(r0 + ty + i) * C + c0 + tx];
  __syncthreads();
#pragma unroll
  for (int i = 0; i < 32; i += 8)
    ob[(long long)(c0 + ty + i) * R + r0 + tx] = (f16)tile[tx][ty + i];
}

// ---------- fused dual-B input GEMM ----------
// A [M,K], B1T/B2T [N,K] f16. Y = gelu_tanh(A@B1 + b1) f16; X2 = (A@B2 + b2) f16.
__global__ __launch_bounds__(256, 2) void gemm_dual(
    const f16* __restrict__ A, const f16* __restrict__ B1T, const f16* __restrict__ B2T,
    const float* __restrict__ b1, const float* __restrict__ b2,
    f16* __restrict__ Y, f16* __restrict__ X2, int M, int N, int K) {
  __shared__ __align__(16) f16 As[128 * 32];
  __shared__ __align__(16) f16 B1s[128 * 32];
  __shared__ __align__(16) f16 B2s[128 * 32];
  const int m0 = blockIdx.x * 128, n0 = blockIdx.y * 128;
  const int t = threadIdx.x;
  const int lane = t & 63, wave = t >> 6;
  const int wr = (wave >> 1) * 64, wc = (wave & 1) * 64;
  const int l15 = lane & 15, quad = lane >> 4;
  const int srow = t >> 2, scol = (t & 3) * 8;

  const f16* Ag = A + (long long)(m0 + srow) * K + scol;
  const f16* B1g = B1T + (long long)(n0 + srow) * K + scol;
  const f16* B2g = B2T + (long long)(n0 + srow) * K + scol;

  f32x4 c1[4][4] = {};
  f32x4 c2[4][4] = {};
  for (int k0 = 0; k0 < K; k0 += 32) {
    gl2lds16(Ag, &As[t * 8]);   gl2lds16(Ag + (long long)64 * K, &As[64 * 32 + t * 8]);
    gl2lds16(B1g, &B1s[t * 8]); gl2lds16(B1g + (long long)64 * K, &B1s[64 * 32 + t * 8]);
    gl2lds16(B2g, &B2s[t * 8]); gl2lds16(B2g + (long long)64 * K, &B2s[64 * 32 + t * 8]);
    Ag += 32; B1g += 32; B2g += 32;
    __syncthreads();
    f16x8 af[4], b1f[4], b2f[4];
#pragma unroll
    for (int i = 0; i < 4; ++i)
      af[i] = *(const f16x8*)&As[(wr + i * 16 + l15) * 32 + quad * 8];
#pragma unroll
    for (int j = 0; j < 4; ++j) {
      b1f[j] = *(const f16x8*)&B1s[(wc + j * 16 + l15) * 32 + quad * 8];
      b2f[j] = *(const f16x8*)&B2s[(wc + j * 16 + l15) * 32 + quad * 8];
    }
#pragma unroll
    for (int i = 0; i < 4; ++i)
#pragma unroll
      for (int j = 0; j < 4; ++j) {
        c1[i][j] = __builtin_amdgcn_mfma_f32_16x16x32_f16(af[i], b1f[j], c1[i][j], 0, 0, 0);
        c2[i][j] = __builtin_amdgcn_mfma_f32_16x16x32_f16(af[i], b2f[j], c2[i][j], 0, 0, 0);
      }
    __syncthreads();
  }
#pragma unroll
  for (int i = 0; i < 4; ++i) {
#pragma unroll
    for (int j = 0; j < 4; ++j) {
      const int col = n0 + wc + j * 16 + l15;
      const float b1v = b1[col], b2v = b2[col];
      const int row0 = m0 + wr + i * 16 + quad * 4;
#pragma unroll
      for (int r = 0; r < 4; ++r) {
        long long off = (long long)(row0 + r) * N + col;
        float v = c1[i][j][r] + b1v;
        float u = v + 0.044715f * v * v * v;
        float g = 0.5f * v * (1.f + tanhf(0.7978845608028654f * u));
        Y[off] = (f16)g;
        X2[off] = (f16)(c2[i][j][r] + b2v);
      }
    }
  }
}

// ---------- GEMM: C[M,N] = A[M,K] @ BT[N,K]^T + bias (fp32 out) ----------
__global__ __launch_bounds__(256, 2) void gemm_bt(
    const f16* __restrict__ A, const f16* __restrict__ BT, const float* __restrict__ bias,
    float* __restrict__ Cf, int M, int N, int K) {
  __shared__ __align__(16) f16 As[128 * 32];
  __shared__ __align__(16) f16 Bs[128 * 32];
  const int m0 = blockIdx.x * 128, n0 = blockIdx.y * 128;
  const int t = threadIdx.x;
  const int lane = t & 63, wave = t >> 6;
  const int wr = (wave >> 1) * 64, wc = (wave & 1) * 64;
  const int l15 = lane & 15, quad = lane >> 4;
  const int srow = t >> 2, scol = (t & 3) * 8;

  const f16* Ag = A + (long long)(m0 + srow) * K + scol;
  const f16* Bg = BT + (long long)(n0 + srow) * K + scol;

  f32x4 acc[4][4] = {};
  for (int k0 = 0; k0 < K; k0 += 32) {
    gl2lds16(Ag, &As[t * 8]); gl2lds16(Ag + (long long)64 * K, &As[64 * 32 + t * 8]);
    gl2lds16(Bg, &Bs[t * 8]); gl2lds16(Bg + (long long)64 * K, &Bs[64 * 32 + t * 8]);
    Ag += 32; Bg += 32;
    __syncthreads();
    f16x8 af[4], bf[4];
#pragma unroll
    for (int i = 0; i < 4; ++i)
      af[i] = *(const f16x8*)&As[(wr + i * 16 + l15) * 32 + quad * 8];
#pragma unroll
    for (int j = 0; j < 4; ++j)
      bf[j] = *(const f16x8*)&Bs[(wc + j * 16 + l15) * 32 + quad * 8];
#pragma unroll
    for (int i = 0; i < 4; ++i)
#pragma unroll
      for (int j = 0; j < 4; ++j)
        acc[i][j] = __builtin_amdgcn_mfma_f32_16x16x32_f16(af[i], bf[j], acc[i][j], 0, 0, 0);
    __syncthreads();
  }
#pragma unroll
  for (int i = 0; i < 4; ++i) {
#pragma unroll
    for (int j = 0; j < 4; ++j) {
      const int col = n0 + wc + j * 16 + l15;
      const float bv = bias[col];
      const int row0 = m0 + wr + i * 16 + quad * 4;
#pragma unroll
      for (int r = 0; r < 4; ++r)
        Cf[(long long)(row0 + r) * N + col] = acc[i][j][r] + bv;
    }
  }
}

// ---------- fused conv + block-diag dual gate GEMM + RG-LRU + chunk summaries ----------
// Block: 128 m-rows (= one scan chunk) x 128 L-cols; head h = blockIdx.y>>1.
// LDS As holds the conv'd A tile [128 x 256] f16, XOR-swizzled 16B granules.
__global__ __launch_bounds__(256, 2) void gates_fused(
    const f16* __restrict__ XBh, const float* __restrict__ cw, const float* __restrict__ cb,
    const f16* __restrict__ BiT, const f16* __restrict__ BaT,
    const float* __restrict__ ib, const float* __restrict__ ab,
    const float* __restrict__ a_param, const int* __restrict__ segpos,
    uint32_t* __restrict__ AN, float* __restrict__ Ac, float* __restrict__ Hc) {
  __shared__ __align__(16) f16 As[128 * 256];   // 64 KB
  __shared__ __align__(16) f16 Bi[128 * 32];    // 8 KB  (reused as carry after k-loop)
  __shared__ __align__(16) f16 Ba[128 * 32];    // 8 KB  -> 80 KB total, 2 blocks/CU
  const int m0 = blockIdx.x * 128;
  const int h = blockIdx.y >> 1;
  const int half = blockIdx.y & 1;
  const int ncol0 = h * HDIM + half * 128;
  const int t = threadIdx.x;
  const int lane = t & 63, wave = t >> 6;
  const int wr = (wave >> 1) * 64, wc = (wave & 1) * 64;
  const int l15 = lane & 15, quad = lane >> 4;

  // ---- conv prologue: As[r][k] = conv(m0+r, h*256+k), swizzled granules ----
#pragma unroll 4
  for (int it = 0; it < 16; ++it) {
    int idx = it * 256 + t;
    int r = idx >> 5, kc = idx & 31;          // granule kc = 8 f16 = 16 B
    int m = m0 + r, tpos = m & (TSEQ - 1);
    int colbase = h * HDIM + kc * 8;
    float acc[8];
    {
      float4 c0 = *(const float4*)&cb[colbase];
      float4 c1 = *(const float4*)&cb[colbase + 4];
      acc[0] = c0.x; acc[1] = c0.y; acc[2] = c0.z; acc[3] = c0.w;
      acc[4] = c1.x; acc[5] = c1.y; acc[6] = c1.z; acc[7] = c1.w;
    }
#pragma unroll
    for (int d = 0; d < 4; ++d) {
      if (tpos >= d) {
        f16x8 xv = *(const f16x8*)&XBh[(long long)(m - d) * LRU + colbase];
        float4 w0 = *(const float4*)&cw[(3 - d) * LRU + colbase];
        float4 w1 = *(const float4*)&cw[(3 - d) * LRU + colbase + 4];
        acc[0] += w0.x * (float)xv[0]; acc[1] += w0.y * (float)xv[1];
        acc[2] += w0.z * (float)xv[2]; acc[3] += w0.w * (float)xv[3];
        acc[4] += w1.x * (float)xv[4]; acc[5] += w1.y * (float)xv[5];
        acc[6] += w1.z * (float)xv[6]; acc[7] += w1.w * (float)xv[7];
      }
    }
    f16x8 o;
#pragma unroll
    for (int k = 0; k < 8; ++k) o[k] = (f16)acc[k];
    int gs = (kc & ~7) | ((kc ^ r) & 7);      // XOR bank-group swizzle
    *(f16x8*)&As[r * 256 + gs * 8] = o;
  }
  __syncthreads();

  // ---- dual GEMM k-loop over the head's 256 k-cols ----
  const int srow = t >> 2, scol = (t & 3) * 8;
  const f16* Big = BiT + (long long)(ncol0 + srow) * HDIM + scol;
  const f16* Bag = BaT + (long long)(ncol0 + srow) * HDIM + scol;
  f32x4 ci[4][4] = {};
  f32x4 ca[4][4] = {};
  for (int k0 = 0; k0 < HDIM; k0 += 32) {
    gl2lds16(Big, &Bi[t * 8]); gl2lds16(Big + 64 * HDIM, &Bi[64 * 32 + t * 8]);
    gl2lds16(Bag, &Ba[t * 8]); gl2lds16(Bag + 64 * HDIM, &Ba[64 * 32 + t * 8]);
    Big += 32; Bag += 32;
    __syncthreads();
    f16x8 af[4], bif[4], baf[4];
#pragma unroll
    for (int i = 0; i < 4; ++i) {
      int row = wr + i * 16 + l15;
      int g = (k0 >> 3) + quad;
      int gsw = (g & ~7) | ((g ^ row) & 7);
      af[i] = *(const f16x8*)&As[row * 256 + gsw * 8];
    }
#pragma unroll
    for (int j = 0; j < 4; ++j) {
      bif[j] = *(const f16x8*)&Bi[(wc + j * 16 + l15) * 32 + quad * 8];
      baf[j] = *(const f16x8*)&Ba[(wc + j * 16 + l15) * 32 + quad * 8];
    }
#pragma unroll
    for (int i = 0; i < 4; ++i)
#pragma unroll
      for (int j = 0; j < 4; ++j) {
        ci[i][j] = __builtin_amdgcn_mfma_f32_16x16x32_f16(af[i], bif[j], ci[i][j], 0, 0, 0);
        ca[i][j] = __builtin_amdgcn_mfma_f32_16x16x32_f16(af[i], baf[j], ca[i][j], 0, 0, 0);
      }
    __syncthreads();
  }

  // ---- epilogue: RG-LRU elementwise, pack AN, and per-column chunk summaries ----
  const int mb = m0 >> 12;                 // batch index (4096 rows/batch)
  const int cch = (m0 & (TSEQ - 1)) >> 7;  // chunk within batch
  float Aw[4], hw[4];                      // per-j wave-level (64-row) summaries
#pragma unroll
  for (int j = 0; j < 4; ++j) {
    const int cl = wc + j * 16 + l15;      // tile-local col 0..127
    const int col = ncol0 + cl;
    const float ibv = ib[col], abv = ab[col];
    const float sp = log1pf(expf(a_param[col]));
    float A4[4], h4[4];
#pragma unroll
    for (int i = 0; i < 4; ++i) {
      float Aseg = 1.f, hseg = 0.f;
#pragma unroll
      for (int r = 0; r < 4; ++r) {
        const int rowL = wr + i * 16 + quad * 4 + r;
        const int row = m0 + rowL;
        float gx = sigmoidf_(ci[i][j][r] + ibv);
        float ga = sigmoidf_(ca[i][j][r] + abv);
        float la = -8.f * ga * sp;
        bool rs = (segpos[row] == 0);
        float a = rs ? 0.f : expf(la);
        uint32_t afx = __float2uint_rn(a * 65536.f);
        if (afx > 65535u) afx = 65535u;
        float aq = (float)afx * (1.f / 65536.f);
        // conv value from swizzled LDS
        int cfull = half * 128 + cl;
        int g = cfull >> 3, e = cfull & 7;
        int gsw = (g & ~7) | ((g ^ rowL) & 7);
        float cv = (float)As[rowL * 256 + gsw * 8 + e];
        float mult = rs ? 1.f : sqrtf(fmaxf(1.f - aq * aq, 0.f));
        f16 nh = (f16)(cv * gx * mult);
        AN[(long long)row * LRU + col] =
            afx | ((uint32_t)__builtin_bit_cast(uint16_t, nh) << 16);
        float xq = (float)nh;
        hseg = aq * hseg + xq;   // scan over r (rows ascending)
        Aseg *= aq;
      }
      A4[i] = Aseg; h4[i] = hseg;
    }
    // cross-quad composition (rows quad*4.. ascending), Kogge-Stone over stride-16 lanes
#pragma unroll
    for (int i = 0; i < 4; ++i) {
      float A = A4[i], hv = h4[i];
#pragma unroll
      for (int d = 1; d <= 2; d <<= 1) {
        int src = quad >= d ? lane - 16 * d : lane;
        float Ap = __shfl(A, src);
        float hp = __shfl(hv, src);
        if (quad >= d) { hv = A * hp + hv; A = Ap * A; }
      }
      A4[i] = __shfl(A, 48 + l15);   // 16-row block total (from quad 3)
      h4[i] = __shfl(hv, 48 + l15);
    }
    float Awv = 1.f, hwv = 0.f;
#pragma unroll
    for (int i = 0; i < 4; ++i) { hwv = A4[i] * hwv + h4[i]; Awv *= A4[i]; }
    Aw[j] = Awv; hw[j] = hwv;
  }
  // cross-wave composition via LDS (reuse Bi space; k-loop is done)
  float* carry = (float*)Bi;   // [128 cols][2]
  __syncthreads();
  if (wr == 0 && quad == 0) {
#pragma unroll
    for (int j = 0; j < 4; ++j) {
      int cl = wc + j * 16 + l15;
      carry[cl * 2] = Aw[j]; carry[cl * 2 + 1] = hw[j];
    }
  }
  __syncthreads();
  if (wr == 64 && quad == 0) {
#pragma unroll
    for (int j = 0; j < 4; ++j) {
      int cl = wc + j * 16 + l15;
      float At = carry[cl * 2], ht = carry[cl * 2 + 1];
      float A = At * Aw[j];
      float hv = Aw[j] * ht + hw[j];
      int o = (mb * NC + cch) * LRU + ncol0 + cl;
      Ac[o] = A; Hc[o] = hv;
    }
  }
}

// ---------- merged scan pass 2+3: recompute chunk prefix, apply, emit G ----------
__global__ void scan23_kernel(const uint32_t* __restrict__ AN,
                              const float* __restrict__ Ac, const float* __restrict__ Hc,
                              const f16* __restrict__ Yh, f16* __restrict__ G) {
  int l = blockIdx.x * 256 + threadIdx.x;
  int c = blockIdx.y, b = blockIdx.z;
  // chunk-prefix over chunks < c (Ac/Hc are tiny, L2-resident)
  float hv = 0.f;
  for (int cc = 0; cc < c; ++cc) {
    int o = (b * NC + cc) * LRU + l;
    hv = Ac[o] * hv + Hc[o];
  }
  long long base = ((long long)b * TSEQ + (long long)c * CT) * LRU + l;
#pragma unroll 4
  for (int s = 0; s < CT; ++s) {
    long long o = base + (long long)s * LRU;
    uint32_t p = AN[o];
    float a = (float)(p & 0xFFFFu) * (1.f / 65536.f);
    float x = f16bits_to_f(p >> 16);
    hv = a * hv + x;
    G[o] = (f16)(hv * (float)Yh[o]);
  }
}

extern "C" void kernel_launch(void* const* d_in, const int* in_sizes, int n_in,
                              void* d_out, int out_size, void* d_ws, size_t ws_size,
                              hipStream_t stream) {
  (void)in_sizes; (void)n_in; (void)out_size; (void)ws_size;
  const float* x          = (const float*)d_in[0];
  const int*   segment_pos= (const int*)d_in[1];
  const float* w_y        = (const float*)d_in[2];
  const float* b_y        = (const float*)d_in[3];
  const float* w_x        = (const float*)d_in[4];
  const float* b_x        = (const float*)d_in[5];
  const float* w_out      = (const float*)d_in[6];
  const float* b_out      = (const float*)d_in[7];
  const float* conv_w     = (const float*)d_in[8];
  const float* conv_b     = (const float*)d_in[9];
  const float* a_param    = (const float*)d_in[10];
  const float* igate_w    = (const float*)d_in[11];
  const float* igate_b    = (const float*)d_in[12];
  const float* agate_w    = (const float*)d_in[13];
  const float* agate_b    = (const float*)d_in[14];
  float* out = (float*)d_out;

  char* base = (char*)d_ws;
  size_t off = 0;
  auto alloc = [&](size_t nbytes) -> void* {
    void* p = base + off;
    off = (off + nbytes + 255) & ~(size_t)255;
    return p;
  };
  f16*     Xh    = (f16*)alloc((size_t)MTOT * LRU * 2);
  f16*     Yh    = (f16*)alloc((size_t)MTOT * LRU * 2);
  f16*     XBh   = (f16*)alloc((size_t)MTOT * LRU * 2);
  uint32_t* AN   = (uint32_t*)alloc((size_t)MTOT * LRU * 4);
  f16*     wyT   = (f16*)alloc((size_t)WID * LRU * 2);
  f16*     wxT   = (f16*)alloc((size_t)WID * LRU * 2);
  f16*     woutT = (f16*)alloc((size_t)LRU * WID * 2);
  f16*     igwT  = (f16*)alloc((size_t)NHEAD * HDIM * HDIM * 2);
  f16*     agwT  = (f16*)alloc((size_t)NHEAD * HDIM * HDIM * 2);
  float*   Ac    = (float*)alloc((size_t)BATCH * NC * LRU * 4);
  float*   Hc    = (float*)alloc((size_t)BATCH * NC * LRU * 4);
  f16*     G     = Xh;   // Xh dead after gemm_dual

  // prep: cast + all weight transposes in one launch
  prep_kernel<<<29696, 256, 0, stream>>>(x, Xh, w_y, w_x, w_out, wyT, wxT, woutT,
                                         igate_w, agate_w, igwT, agwT);
  // fused dual input GEMM (linear_y + gelu, linear_x)
  gemm_dual<<<dim3(MTOT / 128, LRU / 128), 256, 0, stream>>>(
      Xh, wyT, wxT, b_y, b_x, Yh, XBh, MTOT, LRU, WID);
  // fused conv + gates + RG-LRU + chunk summaries
  gates_fused<<<dim3(MTOT / 128, 2 * NHEAD), 256, 0, stream>>>(
      XBh, conv_w, conv_b, igwT, agwT, igate_b, agate_b, a_param, segment_pos, AN, Ac, Hc);
  // merged chunk-prefix + final scan + G emission
  scan23_kernel<<<dim3(LRU / 256, NC, BATCH), 256, 0, stream>>>(AN, Ac, Hc, Yh, G);
  // output projection
  gemm_bt<<<dim3(MTOT / 128, WID / 128), 256, 0, stream>>>(G, woutT, b_out, out, MTOT, WID, LRU);
}